// Round 8
// baseline (192.002 us; speedup 1.0000x reference)
//
#include <hip/hip_runtime.h>
#include <stdint.h>

typedef unsigned short u16;
typedef short s16x8 __attribute__((ext_vector_type(8)));
typedef unsigned short u16x8 __attribute__((ext_vector_type(8)));
typedef unsigned short u16x4 __attribute__((ext_vector_type(4)));
typedef float f32x4 __attribute__((ext_vector_type(4)));
typedef float f32x16 __attribute__((ext_vector_type(16)));
typedef unsigned int u32x2 __attribute__((ext_vector_type(2)));
typedef unsigned int u32x4 __attribute__((ext_vector_type(4)));

#if __has_builtin(__builtin_amdgcn_exp2f)
#define EXP2F(x) __builtin_amdgcn_exp2f(x)
#else
#define EXP2F(x) exp2f(x)
#endif

#define QSCALE 0.18033688011112042f  // 0.125 * log2(e): scores in exp2 domain

__device__ __forceinline__ u16 f2b(float f) {
  union { float f; uint32_t u; } v; v.f = f;
  uint32_t r = (v.u + 0x7fffu + ((v.u >> 16) & 1u)) >> 16;
  return (u16)r;
}

// pack high halves of two f32 bit patterns: result = hi16(lo) | hi16(hi)<<16
__device__ __forceinline__ uint32_t pkhi(uint32_t hi, uint32_t lo) {
#if __has_builtin(__builtin_amdgcn_perm)
  return __builtin_amdgcn_perm(hi, lo, 0x07060302u);
#else
  return (lo >> 16) | (hi & 0xffff0000u);
#endif
}

// v_permlane32_swap_b32: a_new = [a_lo | b_lo], b_new = [a_hi | b_hi]
__device__ __forceinline__ void plswap(uint32_t& a, uint32_t& b) {
#if __has_builtin(__builtin_amdgcn_permlane32_swap)
  typedef unsigned int uv2 __attribute__((ext_vector_type(2)));
  uv2 r = __builtin_amdgcn_permlane32_swap(a, b, false, false);
  a = r[0];
  b = r[1];
#else
  asm volatile("v_permlane32_swap_b32 %0, %1" : "+v"(a), "+v"(b));
#endif
}

// CK-style barrier: waits LDS only, leaves global loads in flight
__device__ __forceinline__ void sync_lds() {
  asm volatile("s_waitcnt lgkmcnt(0)\ns_barrier" ::: "memory");
}

// ---------------------------------------------------------------------------
// Fused prep: blocks [0,2048): cast x -> bf16; [2048,5120): transpose w_qkv;
// [5120,6144): transpose w_out.
// ---------------------------------------------------------------------------
__global__ __launch_bounds__(256)
void prep(const float* __restrict__ x, u16* __restrict__ xb,
          const float* __restrict__ w_qkv, u16* __restrict__ wqT,
          const float* __restrict__ w_out, u16* __restrict__ woT) {
  __shared__ float tile[32][33];
  const int bid = blockIdx.x;
  const int t = threadIdx.x;
  if (bid < 2048) {
    const size_t i = ((size_t)bid * 256 + t) * 8;
    f32x4 v0 = *(const f32x4*)(x + i);
    f32x4 v1 = *(const f32x4*)(x + i + 4);
    u16x8 u;
#pragma unroll
    for (int j = 0; j < 4; j++) { u[j] = f2b(v0[j]); u[4 + j] = f2b(v1[j]); }
    *(u16x8*)(xb + i) = u;
    return;
  }
  const float* src;
  u16* dst;
  int N, nb, kb;
  if (bid < 5120) {
    const int b2 = bid - 2048;
    src = w_qkv; dst = wqT; N = 3072;
    nb = (b2 % 96) * 32; kb = (b2 / 96) * 32;
  } else {
    const int b3 = bid - 5120;
    src = w_out; dst = woT; N = 1024;
    nb = (b3 & 31) * 32; kb = (b3 >> 5) * 32;
  }
  const int tx = t & 31, ty = t >> 5;  // 32 x 8
#pragma unroll
  for (int i = 0; i < 4; i++)
    tile[ty + i * 8][tx] = src[(size_t)(kb + ty + i * 8) * N + nb + tx];
  __syncthreads();
#pragma unroll
  for (int i = 0; i < 4; i++)
    dst[(size_t)(nb + ty + i * 8) * 1024 + kb + tx] = f2b(tile[tx][ty + i * 8]);
}

// ---------------------------------------------------------------------------
// GEMM: C[M,N] = A[M,K] * Bt[N,K]^T + bias[N]; A,Bt bf16.
// BK=64, XOR-swizzled LDS, register-prefetch pipeline with CK barrier.
// EPI 0 (WN=2): LDS-repack epilogue -> q (scaled), k [BH][N][D], v^T [BH][D][N]
// EPI 1: fp32 direct stores.
// ---------------------------------------------------------------------------
template <int EPI, int WN>
__global__ __launch_bounds__(256, 3)
void gemm_bt(const u16* __restrict__ A, const u16* __restrict__ Bt,
             const float* __restrict__ bias, float* __restrict__ outF,
             u16* __restrict__ outQ, u16* __restrict__ outK,
             u16* __restrict__ outVt, int M, int N, int K) {
  constexpr int BN = WN * 64;
  constexpr int RW = 4 / WN;
  constexpr int MI = 128 / RW / 16;
  constexpr int NBI = WN * 2;
  constexpr int SMEM = (EPI == 0) ? 34816 : (16384 + WN * 8192);
  __shared__ char smem[SMEM];
  u16* As = (u16*)smem;
  u16* Bs = As + 128 * 64;

  const int t = threadIdx.x;
  const int m0 = blockIdx.y * 128, n0 = blockIdx.x * BN;
  const int w = t >> 6, lane = t & 63;
  const int wm = w / WN, wn = w % WN;
  const int quad = lane >> 4, lrow = lane & 15;
  const int r8 = lane >> 3, s8 = lane & 7;
  const int csw = (s8 ^ r8) * 8;

  const u16* gA = A + (size_t)(m0 + w * 32 + r8) * K + csw;
  const u16* gB = Bt + (size_t)(n0 + w * (WN * 16) + r8) * K + csw;
  u16* wAs = As + (w * 32 + r8) * 64 + s8 * 8;
  u16* wBs = Bs + (w * (WN * 16) + r8) * 64 + s8 * 8;

  f32x4 acc[MI][4];
#pragma unroll
  for (int i = 0; i < MI; i++)
#pragma unroll
    for (int j = 0; j < 4; j++) {
      f32x4 z = {0.f, 0.f, 0.f, 0.f};
      acc[i][j] = z;
    }

  u16x8 pa[4], pb[NBI];
#pragma unroll
  for (int i = 0; i < 4; i++) pa[i] = *(const u16x8*)(gA + (size_t)(i * 8) * K);
#pragma unroll
  for (int i = 0; i < NBI; i++) pb[i] = *(const u16x8*)(gB + (size_t)(i * 8) * K);

  const int KT = K >> 6;
  for (int kt = 0; kt < KT; ++kt) {
    sync_lds();
#pragma unroll
    for (int i = 0; i < 4; i++) *(u16x8*)(wAs + i * 8 * 64) = pa[i];
#pragma unroll
    for (int i = 0; i < NBI; i++) *(u16x8*)(wBs + i * 8 * 64) = pb[i];
    if (kt + 1 < KT) {
      const size_t off = (size_t)(kt + 1) * 64;
#pragma unroll
      for (int i = 0; i < 4; i++)
        pa[i] = *(const u16x8*)(gA + (size_t)(i * 8) * K + off);
#pragma unroll
      for (int i = 0; i < NBI; i++)
        pb[i] = *(const u16x8*)(gB + (size_t)(i * 8) * K + off);
    }
    sync_lds();

#pragma unroll
    for (int ks = 0; ks < 2; ks++) {
      s16x8 a[MI], b[4];
#pragma unroll
      for (int i = 0; i < MI; i++)
        a[i] = *(const s16x8*)&As[(wm * (MI * 16) + i * 16 + lrow) * 64 +
                                  (((ks * 4 + quad) ^ (lrow & 7)) * 8)];
#pragma unroll
      for (int j = 0; j < 4; j++)
        b[j] = *(const s16x8*)&Bs[(wn * 64 + j * 16 + lrow) * 64 +
                                  (((ks * 4 + quad) ^ (lrow & 7)) * 8)];
#pragma unroll
      for (int i = 0; i < MI; i++)
#pragma unroll
        for (int j = 0; j < 4; j++)
          acc[i][j] = __builtin_amdgcn_mfma_f32_16x16x32_bf16(a[i], b[j],
                                                              acc[i][j], 0, 0, 0);
    }
  }

  if (EPI == 1) {
#pragma unroll
    for (int i = 0; i < MI; i++) {
      const int row = m0 + wm * (MI * 16) + i * 16 + quad * 4;
#pragma unroll
      for (int j = 0; j < 4; j++) {
        const int col = n0 + wn * 64 + j * 16 + lrow;
        const float bv = bias[col];
#pragma unroll
        for (int r = 0; r < 4; r++)
          outF[(size_t)(row + r) * N + col] = acc[i][j][r] + bv;
      }
    }
    return;
  }

  // EPI 0 (WN=2): per-wave 64x64 repack through LDS, coalesced 16B stores
  sync_lds();
  u16* rp = (u16*)smem + w * (64 * 68);
  const int cb = n0 + wn * 64;
  const int which = cb >> 10;
  const int h = (cb & 1023) >> 6;
  const int rbase = m0 + wm * 64;
  const int bb = rbase >> 11, nn0 = rbase & 2047;
  const int rl = lane >> 3, cc = (lane & 7) * 8;

  if (which != 2) {
    const float s = (which == 0) ? QSCALE : 1.0f;
#pragma unroll
    for (int i = 0; i < 4; i++)
#pragma unroll
      for (int j = 0; j < 4; j++) {
        const float bv = bias[cb + j * 16 + lrow];
#pragma unroll
        for (int r = 0; r < 4; r++)
          rp[(i * 16 + quad * 4 + r) * 68 + j * 16 + lrow] =
              f2b((acc[i][j][r] + bv) * s);
      }
    u16* dst = ((which == 0) ? outQ : outK) +
               ((size_t)(bb * 16 + h) * 2048 + nn0) * 64;
#pragma unroll
    for (int it = 0; it < 8; it++) {
      const int row = it * 8 + rl;
      *(u16x8*)&dst[(size_t)row * 64 + cc] = *(const u16x8*)&rp[row * 68 + cc];
    }
  } else {
#pragma unroll
    for (int i = 0; i < 4; i++)
#pragma unroll
      for (int j = 0; j < 4; j++) {
        const float bv = bias[cb + j * 16 + lrow];
        u16x4 pk;
#pragma unroll
        for (int r = 0; r < 4; r++) pk[r] = f2b(acc[i][j][r] + bv);
        *(u16x4*)&rp[(j * 16 + lrow) * 68 + i * 16 + quad * 4] = pk;
      }
    u16* dst = outVt + ((size_t)(bb * 16 + h) * 64) * 2048 + nn0;
#pragma unroll
    for (int it = 0; it < 8; it++) {
      const int d = it * 8 + rl;
      *(u16x8*)&dst[(size_t)d * 2048 + cc] = *(const u16x8*)&rp[d * 68 + cc];
    }
  }
}

// ---------------------------------------------------------------------------
// Flash attention v8: NO LDS, NO barriers in the K-loop.
// Block = 2 waves x 64 q (one 64-q tile); wave w covers keys [w*1024,+1024),
// 32 iters of 32 keys. All MFMA A-operands (K rows, Vt rows) loaded straight
// global->VGPR with one-iter register prefetch; Q in regs; P via
// v_permlane32_swap (R7). li = VALU sums of TRUNCATED p (consistent with PV)
// + shfl_xor(32) at epilogue. End: one barrier, wave1's partials combined
// through a [slot][lane] LDS buffer (conflict-free), wave0 normalizes+stores.
// 32x32 C/D: col=lane&31, row=(reg&3)+8*(reg>>2)+4*(lane>>5).
// ---------------------------------------------------------------------------
__global__ __launch_bounds__(128, 2)
void attn_kernel(const u16* __restrict__ Q, const u16* __restrict__ Kg,
                 const u16* __restrict__ Vt, u16* __restrict__ AO) {
  __shared__ float Osh[64][64];  // [slot = qg*32+dt*16+e][lane]
  __shared__ float Lsh[2][32];

  const int t = threadIdx.x;
  const int bh = blockIdx.x;  // 0..31; linear%8 = bh%8 -> per-head KV on one XCD
  const int qt = blockIdx.y;  // 0..31 (64-q tiles)
  const int w = t >> 6, lane = t & 63;
  const int l31 = lane & 31, lh = lane >> 5;
  const size_t base = (size_t)bh * 2048 * 64;

  // Q frags (loaded once): qg 0/1: B[n=q=qg*32+l31][k=ks*16+lh*8+j]
  s16x8 qf[2][4];
#pragma unroll
  for (int qg = 0; qg < 2; qg++) {
    const u16* qp =
        Q + base + (size_t)(qt * 64 + qg * 32 + l31) * 64 + lh * 8;
#pragma unroll
    for (int ks = 0; ks < 4; ks++) qf[qg][ks] = *(const s16x8*)(qp + ks * 16);
  }

  // per-wave key range
  const u16* kp = Kg + base + (size_t)(w * 1024 + l31) * 64 + lh * 8;
  const u16* vp = Vt + base + (size_t)l31 * 2048 + w * 1024 + lh * 8;

  f32x16 ot[2][2];  // [qg][dt]
#pragma unroll
  for (int qg = 0; qg < 2; qg++)
#pragma unroll
    for (int dt = 0; dt < 2; dt++)
#pragma unroll
      for (int e = 0; e < 16; e++) ot[qg][dt][e] = 0.f;
  float li[2] = {0.f, 0.f};

  // prefetch iter 0
  s16x8 kf[4], vf[2][2];
#pragma unroll
  for (int ks = 0; ks < 4; ks++) kf[ks] = *(const s16x8*)(kp + ks * 16);
#pragma unroll
  for (int dt = 0; dt < 2; dt++)
#pragma unroll
    for (int s = 0; s < 2; s++)
      vf[dt][s] = *(const s16x8*)(vp + (size_t)dt * 32 * 2048 + s * 16);

  for (int kt = 0; kt < 32; kt++) {
    // S^T = K . Q^T  (32 keys x 32 q per qg)
    f32x16 sc[2];
#pragma unroll
    for (int qg = 0; qg < 2; qg++)
#pragma unroll
      for (int e = 0; e < 16; e++) sc[qg][e] = 0.f;
#pragma unroll
    for (int ks = 0; ks < 4; ks++) {
      sc[0] = __builtin_amdgcn_mfma_f32_32x32x16_bf16(kf[ks], qf[0][ks], sc[0], 0, 0, 0);
      sc[1] = __builtin_amdgcn_mfma_f32_32x32x16_bf16(kf[ks], qf[1][ks], sc[1], 0, 0, 0);
    }
    // prefetch next K tile (kf regs dead after QK issue)
    if (kt + 1 < 32) {
      const u16* kn = kp + (size_t)(kt + 1) * 2048;
#pragma unroll
      for (int ks = 0; ks < 4; ks++) kf[ks] = *(const s16x8*)(kn + ks * 16);
    }

    // exp2 -> truncate to bf16; li from truncated p (exact consistency)
    uint32_t P[2][4][2];
#pragma unroll
    for (int qg = 0; qg < 2; qg++) {
      float rsum = 0.f;
#pragma unroll
      for (int g = 0; g < 4; g++) {
        uint32_t u[4];
#pragma unroll
        for (int r = 0; r < 4; r++) {
          u[r] = __builtin_bit_cast(uint32_t, EXP2F(sc[qg][g * 4 + r]));
          rsum += __builtin_bit_cast(float, u[r] & 0xffff0000u);
        }
        P[qg][g][0] = pkhi(u[1], u[0]);
        P[qg][g][1] = pkhi(u[3], u[2]);
      }
      li[qg] += rsum;
    }

    // O^T += Vt . P^T  (B-frags via permlane32_swap)
#pragma unroll
    for (int gp = 0; gp < 2; gp++) {  // 16-key steps within the 32-key tile
      s16x8 pf[2];
#pragma unroll
      for (int qg = 0; qg < 2; qg++) {
        uint32_t w0 = P[qg][2 * gp][0], w2 = P[qg][2 * gp + 1][0];
        uint32_t w1 = P[qg][2 * gp][1], w3 = P[qg][2 * gp + 1][1];
        plswap(w0, w2);
        plswap(w1, w3);
        u32x4 fw = {w0, w1, w2, w3};
        pf[qg] = __builtin_bit_cast(s16x8, fw);
      }
#pragma unroll
      for (int dt = 0; dt < 2; dt++) {
        ot[0][dt] = __builtin_amdgcn_mfma_f32_32x32x16_bf16(vf[dt][gp], pf[0], ot[0][dt], 0, 0, 0);
        ot[1][dt] = __builtin_amdgcn_mfma_f32_32x32x16_bf16(vf[dt][gp], pf[1], ot[1][dt], 0, 0, 0);
      }
    }
    // prefetch next V tile (vf regs dead after PV issue)
    if (kt + 1 < 32) {
      const u16* vn = vp + (kt + 1) * 32;
#pragma unroll
      for (int dt = 0; dt < 2; dt++)
#pragma unroll
        for (int s = 0; s < 2; s++)
          vf[dt][s] = *(const s16x8*)(vn + (size_t)dt * 32 * 2048 + s * 16);
    }
  }

  // cross-half li (keys with bit2==lh live in this lane's regs)
  float lifull[2];
#pragma unroll
  for (int qg = 0; qg < 2; qg++)
    lifull[qg] = li[qg] + __shfl_xor(li[qg], 32);

  // combine the two key-halves
  if (w == 1) {
#pragma unroll
    for (int qg = 0; qg < 2; qg++) {
#pragma unroll
      for (int dt = 0; dt < 2; dt++)
#pragma unroll
        for (int e = 0; e < 16; e++)
          Osh[qg * 32 + dt * 16 + e][lane] = ot[qg][dt][e];
      if (lh == 0) Lsh[qg][l31] = lifull[qg];
    }
  }
  __syncthreads();
  if (w == 0) {
    const int bb = bh >> 4, h = bh & 15;
#pragma unroll
    for (int qg = 0; qg < 2; qg++) {
      const float inv = 1.0f / (lifull[qg] + Lsh[qg][l31]);
      const int qn = qt * 64 + qg * 32 + l31;
      u16* dst = AO + (size_t)(bb * 2048 + qn) * 1024 + h * 64;
#pragma unroll
      for (int dt = 0; dt < 2; dt++) {
#pragma unroll
        for (int g = 0; g < 4; g++) {
          u16x4 pk;
#pragma unroll
          for (int r = 0; r < 4; r++) {
            const float v =
                ot[qg][dt][g * 4 + r] + Osh[qg * 32 + dt * 16 + g * 4 + r][lane];
            pk[r] = f2b(v * inv);
          }
          *(u16x4*)&dst[dt * 32 + g * 8 + lh * 4] = pk;
        }
      }
    }
  }
}

// ---------------------------------------------------------------------------
extern "C" void kernel_launch(void* const* d_in, const int* in_sizes, int n_in,
                              void* d_out, int out_size, void* d_ws,
                              size_t ws_size, hipStream_t stream) {
  const float* x     = (const float*)d_in[0];  // [2,2048,1024]
  const float* w_qkv = (const float*)d_in[1];  // [1024,3072]
  const float* b_qkv = (const float*)d_in[2];  // [3072]
  const float* w_out = (const float*)d_in[3];  // [1024,1024]
  const float* b_out = (const float*)d_in[4];  // [1024]
  float* out = (float*)d_out;                  // [2,2048,1024]

  char* ws = (char*)d_ws;
  u16* wqT = (u16*)ws; ws += (size_t)3072 * 1024 * 2;
  u16* woT = (u16*)ws; ws += (size_t)1024 * 1024 * 2;
  u16* q   = (u16*)ws; ws += (size_t)32 * 2048 * 64 * 2;
  u16* k   = (u16*)ws; ws += (size_t)32 * 2048 * 64 * 2;
  u16* vt  = (u16*)ws; ws += (size_t)32 * 64 * 2048 * 2;
  u16* xb  = (u16*)ws; ws += (size_t)4096 * 1024 * 2;
  u16* ao  = xb;  // alias: xb dead after QKV GEMM, ao born in attention

  prep<<<dim3(6144), 256, 0, stream>>>(x, xb, w_qkv, wqT, w_out, woT);
  gemm_bt<0, 2><<<dim3(24, 32), 256, 0, stream>>>(xb, wqT, b_qkv, nullptr, q, k,
                                                  vt, 4096, 3072, 1024);
  attn_kernel<<<dim3(32, 32), 128, 0, stream>>>(q, k, vt, ao);
  gemm_bt<1, 1><<<dim3(16, 32), 256, 0, stream>>>(ao, woT, b_out, out, nullptr,
                                                  nullptr, nullptr, 4096, 1024, 1024);
}

// Round 9
// 173.100 us; speedup vs baseline: 1.1092x; 1.1092x over previous
//
#include <hip/hip_runtime.h>
#include <stdint.h>

typedef unsigned short u16;
typedef short s16x8 __attribute__((ext_vector_type(8)));
typedef unsigned short u16x8 __attribute__((ext_vector_type(8)));
typedef unsigned short u16x4 __attribute__((ext_vector_type(4)));
typedef float f32x4 __attribute__((ext_vector_type(4)));
typedef float f32x16 __attribute__((ext_vector_type(16)));
typedef unsigned int u32x2 __attribute__((ext_vector_type(2)));
typedef unsigned int u32x4 __attribute__((ext_vector_type(4)));

#if __has_builtin(__builtin_amdgcn_exp2f)
#define EXP2F(x) __builtin_amdgcn_exp2f(x)
#else
#define EXP2F(x) exp2f(x)
#endif

#define QSCALE 0.18033688011112042f  // 0.125 * log2(e): scores in exp2 domain

__device__ __forceinline__ u16 f2b(float f) {
  union { float f; uint32_t u; } v; v.f = f;
  uint32_t r = (v.u + 0x7fffu + ((v.u >> 16) & 1u)) >> 16;
  return (u16)r;
}

// pack high halves of two f32 bit patterns: result = hi16(lo) | hi16(hi)<<16
__device__ __forceinline__ uint32_t pkhi(uint32_t hi, uint32_t lo) {
#if __has_builtin(__builtin_amdgcn_perm)
  return __builtin_amdgcn_perm(hi, lo, 0x07060302u);
#else
  return (lo >> 16) | (hi & 0xffff0000u);
#endif
}

// v_permlane32_swap_b32: a_new = [a_lo | b_lo], b_new = [a_hi | b_hi]
__device__ __forceinline__ void plswap(uint32_t& a, uint32_t& b) {
#if __has_builtin(__builtin_amdgcn_permlane32_swap)
  typedef unsigned int uv2 __attribute__((ext_vector_type(2)));
  uv2 r = __builtin_amdgcn_permlane32_swap(a, b, false, false);
  a = r[0];
  b = r[1];
#else
  asm volatile("v_permlane32_swap_b32 %0, %1" : "+v"(a), "+v"(b));
#endif
}

// CK-style barrier: waits LDS only, leaves global loads in flight
__device__ __forceinline__ void sync_lds() {
  asm volatile("s_waitcnt lgkmcnt(0)\ns_barrier" ::: "memory");
}

// async global -> LDS, 16B per lane; LDS dest = wave-uniform base + lane*16
__device__ __forceinline__ void gld16(const void* g, void* l) {
  __builtin_amdgcn_global_load_lds((__attribute__((address_space(1))) void*)g,
                                   (__attribute__((address_space(3))) void*)l,
                                   16, 0, 0);
}

// ---------------------------------------------------------------------------
// Fused prep: blocks [0,2048): cast x -> bf16; [2048,5120): transpose w_qkv;
// [5120,6144): transpose w_out.
// ---------------------------------------------------------------------------
__global__ __launch_bounds__(256)
void prep(const float* __restrict__ x, u16* __restrict__ xb,
          const float* __restrict__ w_qkv, u16* __restrict__ wqT,
          const float* __restrict__ w_out, u16* __restrict__ woT) {
  __shared__ float tile[32][33];
  const int bid = blockIdx.x;
  const int t = threadIdx.x;
  if (bid < 2048) {
    const size_t i = ((size_t)bid * 256 + t) * 8;
    f32x4 v0 = *(const f32x4*)(x + i);
    f32x4 v1 = *(const f32x4*)(x + i + 4);
    u16x8 u;
#pragma unroll
    for (int j = 0; j < 4; j++) { u[j] = f2b(v0[j]); u[4 + j] = f2b(v1[j]); }
    *(u16x8*)(xb + i) = u;
    return;
  }
  const float* src;
  u16* dst;
  int N, nb, kb;
  if (bid < 5120) {
    const int b2 = bid - 2048;
    src = w_qkv; dst = wqT; N = 3072;
    nb = (b2 % 96) * 32; kb = (b2 / 96) * 32;
  } else {
    const int b3 = bid - 5120;
    src = w_out; dst = woT; N = 1024;
    nb = (b3 & 31) * 32; kb = (b3 >> 5) * 32;
  }
  const int tx = t & 31, ty = t >> 5;  // 32 x 8
#pragma unroll
  for (int i = 0; i < 4; i++)
    tile[ty + i * 8][tx] = src[(size_t)(kb + ty + i * 8) * N + nb + tx];
  __syncthreads();
#pragma unroll
  for (int i = 0; i < 4; i++)
    dst[(size_t)(nb + ty + i * 8) * 1024 + kb + tx] = f2b(tile[tx][ty + i * 8]);
}

// ---------------------------------------------------------------------------
// GEMM: C[M,N] = A[M,K] * Bt[N,K]^T + bias[N]; A,Bt bf16.
// BK=64, XOR-swizzled LDS, register-prefetch pipeline with CK barrier.
// EPI 0 (WN=2): LDS-repack epilogue -> q (scaled), k [BH][N][D], v^T [BH][D][N]
// EPI 1: fp32 direct stores.
// ---------------------------------------------------------------------------
template <int EPI, int WN>
__global__ __launch_bounds__(256, 3)
void gemm_bt(const u16* __restrict__ A, const u16* __restrict__ Bt,
             const float* __restrict__ bias, float* __restrict__ outF,
             u16* __restrict__ outQ, u16* __restrict__ outK,
             u16* __restrict__ outVt, int M, int N, int K) {
  constexpr int BN = WN * 64;
  constexpr int RW = 4 / WN;
  constexpr int MI = 128 / RW / 16;
  constexpr int NBI = WN * 2;
  constexpr int SMEM = (EPI == 0) ? 34816 : (16384 + WN * 8192);
  __shared__ char smem[SMEM];
  u16* As = (u16*)smem;
  u16* Bs = As + 128 * 64;

  const int t = threadIdx.x;
  const int m0 = blockIdx.y * 128, n0 = blockIdx.x * BN;
  const int w = t >> 6, lane = t & 63;
  const int wm = w / WN, wn = w % WN;
  const int quad = lane >> 4, lrow = lane & 15;
  const int r8 = lane >> 3, s8 = lane & 7;
  const int csw = (s8 ^ r8) * 8;

  const u16* gA = A + (size_t)(m0 + w * 32 + r8) * K + csw;
  const u16* gB = Bt + (size_t)(n0 + w * (WN * 16) + r8) * K + csw;
  u16* wAs = As + (w * 32 + r8) * 64 + s8 * 8;
  u16* wBs = Bs + (w * (WN * 16) + r8) * 64 + s8 * 8;

  f32x4 acc[MI][4];
#pragma unroll
  for (int i = 0; i < MI; i++)
#pragma unroll
    for (int j = 0; j < 4; j++) {
      f32x4 z = {0.f, 0.f, 0.f, 0.f};
      acc[i][j] = z;
    }

  u16x8 pa[4], pb[NBI];
#pragma unroll
  for (int i = 0; i < 4; i++) pa[i] = *(const u16x8*)(gA + (size_t)(i * 8) * K);
#pragma unroll
  for (int i = 0; i < NBI; i++) pb[i] = *(const u16x8*)(gB + (size_t)(i * 8) * K);

  const int KT = K >> 6;
  for (int kt = 0; kt < KT; ++kt) {
    sync_lds();
#pragma unroll
    for (int i = 0; i < 4; i++) *(u16x8*)(wAs + i * 8 * 64) = pa[i];
#pragma unroll
    for (int i = 0; i < NBI; i++) *(u16x8*)(wBs + i * 8 * 64) = pb[i];
    if (kt + 1 < KT) {
      const size_t off = (size_t)(kt + 1) * 64;
#pragma unroll
      for (int i = 0; i < 4; i++)
        pa[i] = *(const u16x8*)(gA + (size_t)(i * 8) * K + off);
#pragma unroll
      for (int i = 0; i < NBI; i++)
        pb[i] = *(const u16x8*)(gB + (size_t)(i * 8) * K + off);
    }
    sync_lds();

#pragma unroll
    for (int ks = 0; ks < 2; ks++) {
      s16x8 a[MI], b[4];
#pragma unroll
      for (int i = 0; i < MI; i++)
        a[i] = *(const s16x8*)&As[(wm * (MI * 16) + i * 16 + lrow) * 64 +
                                  (((ks * 4 + quad) ^ (lrow & 7)) * 8)];
#pragma unroll
      for (int j = 0; j < 4; j++)
        b[j] = *(const s16x8*)&Bs[(wn * 64 + j * 16 + lrow) * 64 +
                                  (((ks * 4 + quad) ^ (lrow & 7)) * 8)];
#pragma unroll
      for (int i = 0; i < MI; i++)
#pragma unroll
        for (int j = 0; j < 4; j++)
          acc[i][j] = __builtin_amdgcn_mfma_f32_16x16x32_bf16(a[i], b[j],
                                                              acc[i][j], 0, 0, 0);
    }
  }

  if (EPI == 1) {
#pragma unroll
    for (int i = 0; i < MI; i++) {
      const int row = m0 + wm * (MI * 16) + i * 16 + quad * 4;
#pragma unroll
      for (int j = 0; j < 4; j++) {
        const int col = n0 + wn * 64 + j * 16 + lrow;
        const float bv = bias[col];
#pragma unroll
        for (int r = 0; r < 4; r++)
          outF[(size_t)(row + r) * N + col] = acc[i][j][r] + bv;
      }
    }
    return;
  }

  // EPI 0 (WN=2): per-wave 64x64 repack through LDS, coalesced 16B stores
  sync_lds();
  u16* rp = (u16*)smem + w * (64 * 68);
  const int cb = n0 + wn * 64;
  const int which = cb >> 10;
  const int h = (cb & 1023) >> 6;
  const int rbase = m0 + wm * 64;
  const int bb = rbase >> 11, nn0 = rbase & 2047;
  const int rl = lane >> 3, cc = (lane & 7) * 8;

  if (which != 2) {
    const float s = (which == 0) ? QSCALE : 1.0f;
#pragma unroll
    for (int i = 0; i < 4; i++)
#pragma unroll
      for (int j = 0; j < 4; j++) {
        const float bv = bias[cb + j * 16 + lrow];
#pragma unroll
        for (int r = 0; r < 4; r++)
          rp[(i * 16 + quad * 4 + r) * 68 + j * 16 + lrow] =
              f2b((acc[i][j][r] + bv) * s);
      }
    u16* dst = ((which == 0) ? outQ : outK) +
               ((size_t)(bb * 16 + h) * 2048 + nn0) * 64;
#pragma unroll
    for (int it = 0; it < 8; it++) {
      const int row = it * 8 + rl;
      *(u16x8*)&dst[(size_t)row * 64 + cc] = *(const u16x8*)&rp[row * 68 + cc];
    }
  } else {
#pragma unroll
    for (int i = 0; i < 4; i++)
#pragma unroll
      for (int j = 0; j < 4; j++) {
        const float bv = bias[cb + j * 16 + lrow];
        u16x4 pk;
#pragma unroll
        for (int r = 0; r < 4; r++) pk[r] = f2b(acc[i][j][r] + bv);
        *(u16x4*)&rp[(j * 16 + lrow) * 68 + i * 16 + quad * 4] = pk;
      }
    u16* dst = outVt + ((size_t)(bb * 16 + h) * 64) * 2048 + nn0;
#pragma unroll
    for (int it = 0; it < 8; it++) {
      const int d = it * 8 + rl;
      *(u16x8*)&dst[(size_t)d * 2048 + cc] = *(const u16x8*)&rp[d * 68 + cc];
    }
  }
}

// ---------------------------------------------------------------------------
// Flash attention v9: in-block split-K. 512 threads = 8 waves = 2 key-half
// groups x 4 waves. Each half runs the R7 engine (double-buffered gld16
// K/V staging, S^T on 32x32x16, no-max exp2 softmax, P via permlane32_swap,
// li via ones-MFMA) over 1024 keys / 16 iters. Partials merged through LDS.
// Grid 32x16 x 512thr -> 16 waves/CU (2 blocks x 64.5 KB LDS).
// 32x32 C/D: col=lane&31, row=(reg&3)+8*(reg>>2)+4*(lane>>5).
// ---------------------------------------------------------------------------
__global__ __launch_bounds__(512, 4)
void attn_kernel(const u16* __restrict__ Q, const u16* __restrict__ Kg,
                 const u16* __restrict__ Vt, u16* __restrict__ AO) {
  __shared__ u16 Ks[2][2][64 * 64];  // [half][buf][key][d] swizzled (32 KB)
  __shared__ u16 Vs[2][2][64 * 64];  // [half][buf][d][key] swizzled (32 KB)
  __shared__ float Lsh[4][32];

  const int t = threadIdx.x;
  const int bh = blockIdx.x;  // 0..31; linear%8 = bh%8 -> per-head KV per XCD
  const int qt = blockIdx.y;  // 0..15 (128-q tiles)
  const int w = t >> 6, lane = t & 63;
  const int kh = w >> 2, wi = w & 3;  // key half, wave-in-half
  const int l31 = lane & 31, lh = lane >> 5;
  const int srow8 = lane >> 3, chunk = lane & 7;
  const int csw = chunk ^ srow8;
  const size_t base = (size_t)bh * 2048 * 64;

  // Q frags (loaded once): B[n=q=l31][k = ks*16 + lh*8 + j]
  s16x8 qf[4];
  {
    const u16* qp = Q + base + (size_t)(qt * 128 + wi * 32 + l31) * 64 + lh * 8;
#pragma unroll
    for (int ks = 0; ks < 4; ks++) qf[ks] = *(const s16x8*)(qp + ks * 16);
  }

  int cx[4];
#pragma unroll
  for (int ks = 0; ks < 4; ks++) cx[ks] = ((2 * ks + lh) ^ (l31 & 7)) * 8;

  // staging: wave wi of half kh stages K rows [wi*16,+16) and V d-rows
  // [wi*16,+16) of its half's current 64-key tile
  const u16* kgl = Kg + base + (size_t)(kh * 1024 + wi * 16 + srow8) * 64 +
                   csw * 8;
  const u16* vgl = Vt + base + (size_t)(wi * 16 + srow8) * 2048 + kh * 1024 +
                   csw * 8;
  const int lbase = (wi * 16) * 64;

  const short one_bf16 = 0x3F80;
  s16x8 ones = {one_bf16, one_bf16, one_bf16, one_bf16,
                one_bf16, one_bf16, one_bf16, one_bf16};

  f32x16 ot0, ot1, liacc;
#pragma unroll
  for (int e = 0; e < 16; e++) { ot0[e] = 0.f; ot1[e] = 0.f; liacc[e] = 0.f; }

  // prologue: stage tile 0 into buffer 0
  gld16(kgl, &Ks[kh][0][lbase]);
  gld16(kgl + 512, &Ks[kh][0][lbase + 512]);
  gld16(vgl, &Vs[kh][0][lbase]);
  gld16(vgl + (size_t)8 * 2048, &Vs[kh][0][lbase + 512]);

  for (int kt = 0; kt < 16; kt++) {
    const int cur = kt & 1;
    __syncthreads();  // drains tile-kt loads (in flight for a full phase)
    if (kt + 1 < 16) {
      const int nxt = cur ^ 1;
      gld16(kgl + (size_t)(kt + 1) * 4096, &Ks[kh][nxt][lbase]);
      gld16(kgl + (size_t)(kt + 1) * 4096 + 512, &Ks[kh][nxt][lbase + 512]);
      gld16(vgl + (kt + 1) * 64, &Vs[kh][nxt][lbase]);
      gld16(vgl + (kt + 1) * 64 + (size_t)8 * 2048, &Vs[kh][nxt][lbase + 512]);
    }

    // S^T = K . Q^T : key sub-tiles 0-31 / 32-63 of this half's tile
    f32x16 sc0, sc1;
#pragma unroll
    for (int e = 0; e < 16; e++) { sc0[e] = 0.f; sc1[e] = 0.f; }
#pragma unroll
    for (int ks = 0; ks < 4; ks++) {
      s16x8 k0 = *(const s16x8*)&Ks[kh][cur][l31 * 64 + cx[ks]];
      s16x8 k1 = *(const s16x8*)&Ks[kh][cur][(32 + l31) * 64 + cx[ks]];
      sc0 = __builtin_amdgcn_mfma_f32_32x32x16_bf16(k0, qf[ks], sc0, 0, 0, 0);
      sc1 = __builtin_amdgcn_mfma_f32_32x32x16_bf16(k1, qf[ks], sc1, 0, 0, 0);
    }

    // exp2 (raw v_exp_f32), truncate-pack to bf16 pairs in registers
    uint32_t P[2][4][2];  // [tb][g][pair]
#pragma unroll
    for (int tb = 0; tb < 2; tb++) {
      const f32x16& s = tb ? sc1 : sc0;
#pragma unroll
      for (int g = 0; g < 4; g++) {
        uint32_t u[4];
#pragma unroll
        for (int r = 0; r < 4; r++)
          u[r] = __builtin_bit_cast(uint32_t, EXP2F(s[g * 4 + r]));
        P[tb][g][0] = pkhi(u[1], u[0]);
        P[tb][g][1] = pkhi(u[3], u[2]);
      }
    }

    // O^T += Vt . P^T ; li += ones . P^T.  B-frags via permlane32_swap.
#pragma unroll
    for (int tb = 0; tb < 2; tb++) {
#pragma unroll
      for (int gp = 0; gp < 2; gp++) {
        uint32_t w0 = P[tb][2 * gp][0], w2 = P[tb][2 * gp + 1][0];
        uint32_t w1 = P[tb][2 * gp][1], w3 = P[tb][2 * gp + 1][1];
        plswap(w0, w2);
        plswap(w1, w3);
        u32x4 fw = {w0, w1, w2, w3};
        s16x8 pf = __builtin_bit_cast(s16x8, fw);
        const int ks = tb * 2 + gp;
        s16x8 v0 = *(const s16x8*)&Vs[kh][cur][l31 * 64 + cx[ks]];
        s16x8 v1 = *(const s16x8*)&Vs[kh][cur][(32 + l31) * 64 + cx[ks]];
        ot0 = __builtin_amdgcn_mfma_f32_32x32x16_bf16(v0, pf, ot0, 0, 0, 0);
        ot1 = __builtin_amdgcn_mfma_f32_32x32x16_bf16(v1, pf, ot1, 0, 0, 0);
        liacc = __builtin_amdgcn_mfma_f32_32x32x16_bf16(ones, pf, liacc, 0, 0, 0);
      }
    }
  }

  // merge halves: half 1 parks partials in LDS (reuse Ks area = 32 KB),
  // half 0 adds, normalizes, stores. Element identity (q=l31, d) maps to the
  // same (lane, reg) in both halves -> index by raw lane, conflict-free.
  float* Osm = (float*)Ks;
  const float lihalf = liacc[0];  // ones-A: all rows equal, full half-sum
  __syncthreads();                // all frag reads of Ks/Vs done
  if (kh == 1) {
#pragma unroll
    for (int e = 0; e < 16; e++) {
      Osm[((wi * 2 + 0) * 16 + e) * 64 + lane] = ot0[e];
      Osm[((wi * 2 + 1) * 16 + e) * 64 + lane] = ot1[e];
    }
    if (lh == 0) Lsh[wi][l31] = lihalf;
  }
  __syncthreads();
  if (kh == 0) {
    const float inv = 1.0f / (lihalf + Lsh[wi][l31]);
    const int bb = bh >> 4, h = bh & 15;
    const int qn = qt * 128 + wi * 32 + l31;
    u16* dst = AO + (size_t)(bb * 2048 + qn) * 1024 + h * 64;
#pragma unroll
    for (int dt = 0; dt < 2; dt++) {
      const f32x16& o = dt ? ot1 : ot0;
#pragma unroll
      for (int g = 0; g < 4; g++) {
        u16x4 pk;
#pragma unroll
        for (int r = 0; r < 4; r++) {
          const float v =
              o[g * 4 + r] + Osm[((wi * 2 + dt) * 16 + g * 4 + r) * 64 + lane];
          pk[r] = f2b(v * inv);
        }
        *(u16x4*)&dst[dt * 32 + g * 8 + lh * 4] = pk;
      }
    }
  }
}

// ---------------------------------------------------------------------------
extern "C" void kernel_launch(void* const* d_in, const int* in_sizes, int n_in,
                              void* d_out, int out_size, void* d_ws,
                              size_t ws_size, hipStream_t stream) {
  const float* x     = (const float*)d_in[0];  // [2,2048,1024]
  const float* w_qkv = (const float*)d_in[1];  // [1024,3072]
  const float* b_qkv = (const float*)d_in[2];  // [3072]
  const float* w_out = (const float*)d_in[3];  // [1024,1024]
  const float* b_out = (const float*)d_in[4];  // [1024]
  float* out = (float*)d_out;                  // [2,2048,1024]

  char* ws = (char*)d_ws;
  u16* wqT = (u16*)ws; ws += (size_t)3072 * 1024 * 2;
  u16* woT = (u16*)ws; ws += (size_t)1024 * 1024 * 2;
  u16* q   = (u16*)ws; ws += (size_t)32 * 2048 * 64 * 2;
  u16* k   = (u16*)ws; ws += (size_t)32 * 2048 * 64 * 2;
  u16* vt  = (u16*)ws; ws += (size_t)32 * 64 * 2048 * 2;
  u16* xb  = (u16*)ws; ws += (size_t)4096 * 1024 * 2;
  u16* ao  = xb;  // alias: xb dead after QKV GEMM, ao born in attention

  prep<<<dim3(6144), 256, 0, stream>>>(x, xb, w_qkv, wqT, w_out, woT);
  gemm_bt<0, 2><<<dim3(24, 32), 256, 0, stream>>>(xb, wqT, b_qkv, nullptr, q, k,
                                                  vt, 4096, 3072, 1024);
  attn_kernel<<<dim3(32, 16), 512, 0, stream>>>(q, k, vt, ao);
  gemm_bt<1, 1><<<dim3(16, 32), 256, 0, stream>>>(ao, woT, b_out, out, nullptr,
                                                  nullptr, nullptr, 4096, 1024, 1024);
}